// Round 11
// baseline (374.506 us; speedup 1.0000x reference)
//
#include <hip/hip_runtime.h>
#include <hip/hip_bf16.h>

typedef __attribute__((ext_vector_type(8))) short bf16x8;
typedef __attribute__((ext_vector_type(4))) float f32x4;

#define DH 128
#define DOUT 64

static __device__ __forceinline__ unsigned short f2bf(float f) {
    __hip_bfloat16 h = __float2bfloat16(f);
    return *(unsigned short*)&h;
}
// accumulate 2 int8 cols (packed in low/high byte of u) scaled by s
static __device__ __forceinline__ void accI(float& a0, float& a1, unsigned u, float s) {
    int lo = (int)(signed char)(u & 0xffu);
    int hi = (int)(signed char)(u >> 8);
    a0 += s * (float)lo;
    a1 += s * (float)hi;
}

// ---------------- prep: x->int8+scale, weights->bf16 transposed, zero rows, + histogram ----------------
// Histogram is fire-and-forget atomicAdd (no return value) -> wave issues and moves on.

struct WPrep {
    const float* src[8];
    unsigned short* dst[8];
};

__global__ void prep_conv_kernel(const float* __restrict__ x,
                                 char* __restrict__ xq, float* __restrict__ sx,
                                 char* __restrict__ hAq, float* __restrict__ sA,
                                 char* __restrict__ hBq, float* __restrict__ sB,
                                 int nA, WPrep p,
                                 int* __restrict__ cnt,
                                 const int* __restrict__ dstv, int E, int N_) {
    int id = blockIdx.x * blockDim.x + threadIdx.x;
    if (id < nA) {  // nA = N*32 : 32 threads per row, 4 cols each
        float4 v = ((const float4*)x)[id];
        float m = fmaxf(fmaxf(fabsf(v.x), fabsf(v.y)), fmaxf(fabsf(v.z), fabsf(v.w)));
#pragma unroll
        for (int d = 16; d >= 1; d >>= 1) m = fmaxf(m, __shfl_xor(m, d));
        float inv = m > 0.f ? 127.f / m : 0.f;
        int q0 = __float2int_rn(v.x * inv);
        int q1 = __float2int_rn(v.y * inv);
        int q2 = __float2int_rn(v.z * inv);
        int q3 = __float2int_rn(v.w * inv);
        unsigned pk = (q0 & 0xff) | ((q1 & 0xff) << 8) | ((q2 & 0xff) << 16) | ((q3 & 0xff) << 24);
        ((unsigned*)xq)[id] = pk;
        if ((id & 31) == 0) sx[id >> 5] = m * (1.f / 127.f);
        return;
    }
    id -= nA;
    if (id < 7 * 16384 + 8192) {  // weight transpose (bf16, for MFMA)
        int m, off;
        if (id < 7 * 16384) { m = id >> 14; off = id & 16383; }
        else { m = 7; off = id - 7 * 16384; }
        int shift = (m == 7) ? 6 : 7;
        int nc = 1 << shift;
        int k = off >> shift;
        int n = off & (nc - 1);
        p.dst[m][n * 128 + k] = f2bf(p.src[m][off]);
        return;
    }
    id -= 7 * 16384 + 8192;
    if (id < 96) {  // zero row N of the three int8 feature buffers
        int w = id >> 5, j = id & 31;
        unsigned* dst = (unsigned*)(w == 0 ? xq : (w == 1 ? hAq : hBq));
        dst[(size_t)N_ * 32 + j] = 0u;
        return;
    }
    id -= 96;
    if (id < 3) {  // zero scale of row N
        (id == 0 ? sx : (id == 1 ? sA : sB))[N_] = 0.f;
        return;
    }
    id -= 3;
    if (id < E) {  // degree histogram (no return -> cheap)
        int d = dstv[id];
        if ((unsigned)d < (unsigned)N_) atomicAdd(&cnt[d], 1);
    }
}

// ---------------- CSR build (degrees padded x8; esrc holds 16-bit src node ids) ----------------

__global__ void scan1_kernel(const int* __restrict__ cnt, int* __restrict__ rp_part,
                             int* __restrict__ bsum, int n) {
    __shared__ int s[256];
    int tid = threadIdx.x;
    int i = blockIdx.x * 256 + tid;
    int v = (i < n) ? ((cnt[i] + 7) & ~7) : 0;
    s[tid] = v;
    __syncthreads();
    for (int off = 1; off < 256; off <<= 1) {
        int t = (tid >= off) ? s[tid - off] : 0;
        __syncthreads();
        s[tid] += t;
        __syncthreads();
    }
    if (i <= n) rp_part[i] = s[tid] - v;
    if (tid == 255) bsum[blockIdx.x] = s[255];
}

__global__ void scan2_kernel(int* __restrict__ bsum, int nb) {
    __shared__ int s[256];
    int tid = threadIdx.x;
    int v = (tid < nb) ? bsum[tid] : 0;
    s[tid] = v;
    __syncthreads();
    for (int off = 1; off < 256; off <<= 1) {
        int t = (tid >= off) ? s[tid - off] : 0;
        __syncthreads();
        s[tid] += t;
        __syncthreads();
    }
    if (tid < nb) bsum[tid] = s[tid] - v;
}

// row_ptr + per-node fill cursor + pad tail (<=7 slots with zero-row id).
__global__ void scan3a_kernel(const int* __restrict__ rp_part, const int* __restrict__ bsum,
                              int* __restrict__ row_ptr, int* __restrict__ cursor,
                              const int* __restrict__ cnt,
                              unsigned short* __restrict__ esrc, int n) {
    int gid = blockIdx.x * blockDim.x + threadIdx.x;
    if (gid <= n) row_ptr[gid] = rp_part[gid] + bsum[gid >> 8];
    if (gid < n) {
        int st = rp_part[gid] + bsum[gid >> 8];
        cursor[gid] = st;
        int c = cnt[gid];
        int pe = (c + 7) & ~7;
        for (int j = c; j < pe; ++j) esrc[st + j] = (unsigned short)n;
    }
}

// per edge: claim a slot via cursor atomic, scatter 16-bit src id (~1.9MB region, L2-resident).
__global__ void scan3b_kernel(const int* __restrict__ src, const int* __restrict__ dst,
                              int* __restrict__ cursor,
                              unsigned short* __restrict__ esrc, int n, int E) {
    int e = blockIdx.x * blockDim.x + threadIdx.x;
    if (e < E) {
        int d = dst[e];
        if ((unsigned)d < (unsigned)n) {
            int pos = atomicAdd(&cursor[d], 1);
            esrc[pos] = (unsigned short)src[e];
        }
    }
}

// ---------------- fused layer: int8 gather -> GEMM1(relu) -> GEMM2 [-> GEMM3(relu) -> GEMM4] ----------------
// Rounds 0-10: gather floor ~40cy/CU per row, invariant to request width / pipeline depth /
// bytes / chunking / occupancy knobs. int8 rows (128B + per-row fp32 scale) halve HBM traffic.
// This round's floor probe #7: nontemporal gather loads (features ~0.5% L1-hit; nt skips L1
// allocation). NOTE: __launch_bounds__(256,8) correlated with container failures (R6,R9); keep 6.

template <bool HEAD>
__launch_bounds__(256, 6)
__global__ void layer_kernel(const char* __restrict__ hq, const float* __restrict__ sIn,
                             const int* __restrict__ rp,
                             const unsigned short* __restrict__ esrc,
                             const unsigned short* __restrict__ W1t,
                             const float* __restrict__ b1,
                             const unsigned short* __restrict__ W2t,
                             const float* __restrict__ b2,
                             const unsigned short* __restrict__ W3t,
                             const float* __restrict__ b3,
                             const unsigned short* __restrict__ W4t,
                             const float* __restrict__ b4,
                             char* __restrict__ outq, float* __restrict__ outs,
                             float* __restrict__ outp, int M) {
    constexpr int LDA = 128 + 8;
    constexpr int CAP = 1024;
    __shared__ __align__(16) unsigned short As[16][LDA];
    __shared__ __align__(16) unsigned short Zs[16][LDA];
    __shared__ __align__(16) int2 sIdx[CAP];

    int tid = threadIdx.x;
    int wave = __builtin_amdgcn_readfirstlane(tid >> 6);
    int lane = tid & 63;
    int row0 = blockIdx.x * 16;
    int nd0 = row0 + wave * 4;

    const char* hc = hq;
    unsigned voff = (unsigned)lane << 1;   // 2 int8 cols per lane

    int wbv = rp[row0];
    int Cv = rp[min(row0 + 16, M)] - wbv;
    int wb = __builtin_amdgcn_readfirstlane(wbv);
    int C = __builtin_amdgcn_readfirstlane(Cv);

    int b[4], e[4];
#pragma unroll
    for (int i = 0; i < 4; ++i) {
        int ndc = min(nd0 + i, M);
        int nd1 = min(nd0 + i + 1, M);
        b[i] = rp[ndc] - wb;
        e[i] = rp[nd1] - wb;
    }

    float a0[4] = {0.f, 0.f, 0.f, 0.f}, a1[4] = {0.f, 0.f, 0.f, 0.f};

    for (int p0 = 0; p0 < C; p0 += CAP) {
        int cend = min(C, p0 + CAP);
        for (int i = tid; i < cend - p0; i += 256) {
            int id = esrc[wb + p0 + i];
            sIdx[i] = make_int2(id << 7, __float_as_int(sIn[id]));
        }
        __syncthreads();
#pragma unroll
        for (int i = 0; i < 4; ++i) {
            int nb = max(b[i], p0) - p0;
            int ne = min(e[i], cend) - p0;
            if (nb < ne) {
                int2 ia[8];
                unsigned ua[8];
#pragma unroll
                for (int t = 0; t < 8; ++t) ia[t] = sIdx[nb + t];
#pragma unroll
                for (int t = 0; t < 8; ++t)
                    ua[t] = __builtin_nontemporal_load(
                        (const unsigned short*)(hc + (unsigned)ia[t].x + voff));
                for (int r = nb + 8; r < ne; r += 8) {
                    int2 ib[8];
                    unsigned ub[8];
#pragma unroll
                    for (int t = 0; t < 8; ++t) ib[t] = sIdx[r + t];
#pragma unroll
                    for (int t = 0; t < 8; ++t)
                        ub[t] = __builtin_nontemporal_load(
                            (const unsigned short*)(hc + (unsigned)ib[t].x + voff));
#pragma unroll
                    for (int t = 0; t < 8; ++t) accI(a0[i], a1[i], ua[t], __int_as_float(ia[t].y));
#pragma unroll
                    for (int t = 0; t < 8; ++t) { ia[t] = ib[t]; ua[t] = ub[t]; }
                }
#pragma unroll
                for (int t = 0; t < 8; ++t) accI(a0[i], a1[i], ua[t], __int_as_float(ia[t].y));
            }
        }
        __syncthreads();
    }

    // add self, pack bf16 to LDS
#pragma unroll
    for (int i = 0; i < 4; ++i) {
        int ndc = min(nd0 + i, M);
        unsigned su = *(const unsigned short*)(hc + ((size_t)(unsigned)ndc << 7) + voff);
        accI(a0[i], a1[i], su, sIn[ndc]);
        unsigned pv = (unsigned)f2bf(a0[i]) | ((unsigned)f2bf(a1[i]) << 16);
        *(unsigned*)&As[wave * 4 + i][lane * 2] = pv;
    }
    __syncthreads();

    int quad = lane >> 4;
    int l16 = lane & 15;

    // ---- GEMM1: Zs = relu(As @ W1 + b1) ----
    bf16x8 af[4];
#pragma unroll
    for (int kt = 0; kt < 4; ++kt)
        af[kt] = *(const bf16x8*)(&As[l16][kt * 32 + quad * 8]);
#pragma unroll
    for (int p = 0; p < 2; ++p) {
        int ncol = (wave * 2 + p) * 16 + l16;
        const unsigned short* wp = W1t + ncol * 128 + quad * 8;
        f32x4 a = {0.f, 0.f, 0.f, 0.f};
#pragma unroll
        for (int kt = 0; kt < 4; ++kt)
            a = __builtin_amdgcn_mfma_f32_16x16x32_bf16(
                af[kt], *(const bf16x8*)(wp + kt * 32), a, 0, 0, 0);
        float bs = b1[ncol];
#pragma unroll
        for (int r = 0; r < 4; ++r) {
            float v = a[r] + bs;
            if (v < 0.f) v = 0.f;
            Zs[quad * 4 + r][ncol] = f2bf(v);
        }
    }
    __syncthreads();

    // ---- GEMM2: relu(Zs @ W2 + b2) ----
    bf16x8 zf[4];
#pragma unroll
    for (int kt = 0; kt < 4; ++kt)
        zf[kt] = *(const bf16x8*)(&Zs[l16][kt * 32 + quad * 8]);

    if (!HEAD) {
        __shared__ float Fs[16][132];
#pragma unroll
        for (int p = 0; p < 2; ++p) {
            int ncol = (wave * 2 + p) * 16 + l16;
            const unsigned short* wp = W2t + ncol * 128 + quad * 8;
            f32x4 a = {0.f, 0.f, 0.f, 0.f};
#pragma unroll
            for (int kt = 0; kt < 4; ++kt)
                a = __builtin_amdgcn_mfma_f32_16x16x32_bf16(
                    zf[kt], *(const bf16x8*)(wp + kt * 32), a, 0, 0, 0);
            float bs = b2[ncol];
#pragma unroll
            for (int r = 0; r < 4; ++r) {
                float v = a[r] + bs;
                if (v < 0.f) v = 0.f;
                Fs[quad * 4 + r][ncol] = v;
            }
        }
        __syncthreads();
        // quantize 16 rows to int8 + per-row scale (16 threads per row, 8 cols each)
        {
            int row = tid >> 4;
            int c0 = (tid & 15) * 8;
            float v8[8];
            float m = 0.f;
#pragma unroll
            for (int j = 0; j < 8; ++j) { v8[j] = Fs[row][c0 + j]; m = fmaxf(m, v8[j]); }
#pragma unroll
            for (int d = 8; d >= 1; d >>= 1) m = fmaxf(m, __shfl_xor(m, d));
            float inv = m > 0.f ? 127.f / m : 0.f;
            unsigned w0 = 0, w1 = 0;
#pragma unroll
            for (int j = 0; j < 4; ++j) {
                w0 |= (unsigned)(__float2int_rn(v8[j] * inv) & 0xff) << (8 * j);
                w1 |= (unsigned)(__float2int_rn(v8[4 + j] * inv) & 0xff) << (8 * j);
            }
            int grow = row0 + row;
            if (grow < M) {
                uint2 pk = make_uint2(w0, w1);
                ((uint2*)(outq + (size_t)grow * 128))[tid & 15] = pk;
                if ((tid & 15) == 0) outs[grow] = m * (1.f / 127.f);
            }
        }
    } else {
#pragma unroll
        for (int p = 0; p < 2; ++p) {
            int ncol = (wave * 2 + p) * 16 + l16;
            const unsigned short* wp = W2t + ncol * 128 + quad * 8;
            f32x4 a = {0.f, 0.f, 0.f, 0.f};
#pragma unroll
            for (int kt = 0; kt < 4; ++kt)
                a = __builtin_amdgcn_mfma_f32_16x16x32_bf16(
                    zf[kt], *(const bf16x8*)(wp + kt * 32), a, 0, 0, 0);
            float bs = b2[ncol];
#pragma unroll
            for (int r = 0; r < 4; ++r) {
                float v = a[r] + bs;
                if (v < 0.f) v = 0.f;
                As[quad * 4 + r][ncol] = f2bf(v);
            }
        }
        __syncthreads();
        // ---- GEMM3: Zs = relu(As @ W3 + b3) ----
        bf16x8 hf[4];
#pragma unroll
        for (int kt = 0; kt < 4; ++kt)
            hf[kt] = *(const bf16x8*)(&As[l16][kt * 32 + quad * 8]);
#pragma unroll
        for (int p = 0; p < 2; ++p) {
            int ncol = (wave * 2 + p) * 16 + l16;
            const unsigned short* wp = W3t + ncol * 128 + quad * 8;
            f32x4 a = {0.f, 0.f, 0.f, 0.f};
#pragma unroll
            for (int kt = 0; kt < 4; ++kt)
                a = __builtin_amdgcn_mfma_f32_16x16x32_bf16(
                    hf[kt], *(const bf16x8*)(wp + kt * 32), a, 0, 0, 0);
            float bs = b3[ncol];
#pragma unroll
            for (int r = 0; r < 4; ++r) {
                float v = a[r] + bs;
                if (v < 0.f) v = 0.f;
                Zs[quad * 4 + r][ncol] = f2bf(v);
            }
        }
        __syncthreads();
        // ---- GEMM4: d_out = Zs @ W4 + b4 (fp32, 64 cols) ----
        bf16x8 gf[4];
#pragma unroll
        for (int kt = 0; kt < 4; ++kt)
            gf[kt] = *(const bf16x8*)(&Zs[l16][kt * 32 + quad * 8]);
        {
            int ncol = wave * 16 + l16;
            const unsigned short* wp = W4t + ncol * 128 + quad * 8;
            f32x4 a = {0.f, 0.f, 0.f, 0.f};
#pragma unroll
            for (int kt = 0; kt < 4; ++kt)
                a = __builtin_amdgcn_mfma_f32_16x16x32_bf16(
                    gf[kt], *(const bf16x8*)(wp + kt * 32), a, 0, 0, 0);
            float bs = b4[ncol];
#pragma unroll
            for (int r = 0; r < 4; ++r) {
                int grow = row0 + quad * 4 + r;
                if (grow < M)
                    outp[(size_t)grow * 64 + ncol] = a[r] + bs;
            }
        }
    }
}

// ---------------- launch ----------------

extern "C" void kernel_launch(void* const* d_in, const int* in_sizes, int n_in,
                              void* d_out, int out_size, void* d_ws, size_t ws_size,
                              hipStream_t stream) {
    const float* x = (const float*)d_in[0];
    const int* ei = (const int*)d_in[1];
    int N = in_sizes[0] / DH;
    int E = in_sizes[1] / 2;
    const int* src = ei;
    const int* dstv = ei + E;
    int Epad = E + 7 * N + 1024;

    char* ws = (char*)d_ws;
    size_t off = 0;
    auto alloc = [&](size_t bytes) -> void* {
        void* p = ws + off;
        off += (bytes + 255) & ~(size_t)255;
        return p;
    };
    // int8 feature buffers, N+1 rows (row N = zero); per-row fp32 scales
    char* xq  = (char*)alloc((size_t)(N + 1) * 128);
    char* hAq = (char*)alloc((size_t)(N + 1) * 128);
    char* hBq = (char*)alloc((size_t)(N + 1) * 128);
    float* sx = (float*)alloc((size_t)(N + 1) * 4);
    float* sA = (float*)alloc((size_t)(N + 1) * 4);
    float* sB = (float*)alloc((size_t)(N + 1) * 4);
    unsigned short* wt[8];
    for (int m = 0; m < 8; ++m) wt[m] = (unsigned short*)alloc(16384 * 2);
    int* cnt     = (int*)alloc((size_t)N * 4);
    int* cursor  = (int*)alloc((size_t)N * 4);
    int* rp_part = (int*)alloc((size_t)(N + 1) * 4);
    int* row_ptr = (int*)alloc((size_t)(N + 1) * 4);
    int* bsum    = (int*)alloc(256 * 4);
    unsigned short* esrc = (unsigned short*)alloc((size_t)Epad * 2);

    WPrep wp;
    wp.src[0] = (const float*)d_in[2];
    wp.src[1] = (const float*)d_in[4];
    wp.src[2] = (const float*)d_in[6];
    wp.src[3] = (const float*)d_in[8];
    wp.src[4] = (const float*)d_in[10];
    wp.src[5] = (const float*)d_in[12];
    wp.src[6] = (const float*)d_in[14];
    wp.src[7] = (const float*)d_in[16];
    for (int m = 0; m < 8; ++m) wp.dst[m] = wt[m];

    hipMemsetAsync(cnt, 0, (size_t)N * 4, stream);

    int nA = N * 32;
    int conv_items = nA + 7 * 16384 + 8192 + 99 + E;
    prep_conv_kernel<<<(conv_items + 255) / 256, 256, 0, stream>>>(
        x, xq, sx, hAq, sA, hBq, sB, nA, wp, cnt, dstv, E, N);

    int nb = (N + 1 + 255) / 256;
    int eb = (E + 255) / 256;
    scan1_kernel<<<nb, 256, 0, stream>>>(cnt, rp_part, bsum, N);
    scan2_kernel<<<1, 256, 0, stream>>>(bsum, nb);
    scan3a_kernel<<<nb, 256, 0, stream>>>(rp_part, bsum, row_ptr, cursor, cnt, esrc, N);
    scan3b_kernel<<<eb, 256, 0, stream>>>(src, dstv, cursor, esrc, N, E);

    int gb = (N + 15) / 16;

    const float* c1b1 = (const float*)d_in[3];
    const float* c1b2 = (const float*)d_in[5];
    const float* c2b1 = (const float*)d_in[7];
    const float* c2b2 = (const float*)d_in[9];
    const float* c3b1 = (const float*)d_in[11];
    const float* c3b2 = (const float*)d_in[13];
    const float* l1b  = (const float*)d_in[15];
    const float* l2b  = (const float*)d_in[17];

    layer_kernel<false><<<gb, 256, 0, stream>>>(
        xq, sx, row_ptr, esrc, wt[0], c1b1, wt[1], c1b2,
        nullptr, nullptr, nullptr, nullptr, hAq, sA, nullptr, N);
    layer_kernel<false><<<gb, 256, 0, stream>>>(
        hAq, sA, row_ptr, esrc, wt[2], c2b1, wt[3], c2b2,
        nullptr, nullptr, nullptr, nullptr, hBq, sB, nullptr, N);
    layer_kernel<true><<<gb, 256, 0, stream>>>(
        hBq, sB, row_ptr, esrc, wt[4], c3b1, wt[5], c3b2,
        wt[6], l1b, wt[7], l2b, nullptr, nullptr, (float*)d_out, N);
}

// Round 12
// 324.827 us; speedup vs baseline: 1.1529x; 1.1529x over previous
//
#include <hip/hip_runtime.h>
#include <hip/hip_bf16.h>

typedef __attribute__((ext_vector_type(8))) short bf16x8;
typedef __attribute__((ext_vector_type(4))) float f32x4;

#define DH 128
#define DOUT 64

static __device__ __forceinline__ unsigned short f2bf(float f) {
    __hip_bfloat16 h = __float2bfloat16(f);
    return *(unsigned short*)&h;
}
// accumulate 2 int8 cols (packed in low/high byte of u) scaled by s
static __device__ __forceinline__ void accI(float& a0, float& a1, unsigned u, float s) {
    int lo = (int)(signed char)(u & 0xffu);
    int hi = (int)(signed char)(u >> 8);
    a0 += s * (float)lo;
    a1 += s * (float)hi;
}

// ---------------- prep: x->int8+scale, weights->bf16 transposed, zero rows, + histogram ----------------
// Histogram atomic (with rank return) overlaps the 1.6M-thread conversion work (R11 lesson:
// a dedicated dependent-atomic kernel is slower than overlapping it here).

struct WPrep {
    const float* src[8];
    unsigned short* dst[8];
};

__global__ void prep_conv_kernel(const float* __restrict__ x,
                                 char* __restrict__ xq, float* __restrict__ sx,
                                 char* __restrict__ hAq, float* __restrict__ sA,
                                 char* __restrict__ hBq, float* __restrict__ sB,
                                 int nA, WPrep p,
                                 int* __restrict__ cnt, int* __restrict__ rank,
                                 const int* __restrict__ dstv, int E, int N_) {
    int id = blockIdx.x * blockDim.x + threadIdx.x;
    if (id < nA) {  // nA = N*32 : 32 threads per row, 4 cols each
        float4 v = ((const float4*)x)[id];
        float m = fmaxf(fmaxf(fabsf(v.x), fabsf(v.y)), fmaxf(fabsf(v.z), fabsf(v.w)));
#pragma unroll
        for (int d = 16; d >= 1; d >>= 1) m = fmaxf(m, __shfl_xor(m, d));
        float inv = m > 0.f ? 127.f / m : 0.f;
        int q0 = __float2int_rn(v.x * inv);
        int q1 = __float2int_rn(v.y * inv);
        int q2 = __float2int_rn(v.z * inv);
        int q3 = __float2int_rn(v.w * inv);
        unsigned pk = (q0 & 0xff) | ((q1 & 0xff) << 8) | ((q2 & 0xff) << 16) | ((q3 & 0xff) << 24);
        ((unsigned*)xq)[id] = pk;
        if ((id & 31) == 0) sx[id >> 5] = m * (1.f / 127.f);
        return;
    }
    id -= nA;
    if (id < 7 * 16384 + 8192) {  // weight transpose (bf16, for MFMA)
        int m, off;
        if (id < 7 * 16384) { m = id >> 14; off = id & 16383; }
        else { m = 7; off = id - 7 * 16384; }
        int shift = (m == 7) ? 6 : 7;
        int nc = 1 << shift;
        int k = off >> shift;
        int n = off & (nc - 1);
        p.dst[m][n * 128 + k] = f2bf(p.src[m][off]);
        return;
    }
    id -= 7 * 16384 + 8192;
    if (id < 96) {  // zero row N of the three int8 feature buffers
        int w = id >> 5, j = id & 31;
        unsigned* dst = (unsigned*)(w == 0 ? xq : (w == 1 ? hAq : hBq));
        dst[(size_t)N_ * 32 + j] = 0u;
        return;
    }
    id -= 96;
    if (id < 3) {  // zero scale of row N
        (id == 0 ? sx : (id == 1 ? sA : sB))[N_] = 0.f;
        return;
    }
    id -= 3;
    if (id < E) {  // degree histogram + per-edge rank
        int d = dstv[id];
        if ((unsigned)d < (unsigned)N_) rank[id] = atomicAdd(&cnt[d], 1);
    }
}

// ---------------- CSR build (degrees padded x8; esrc holds 16-bit src node ids) ----------------
// scan1 fuses scan2: last-arriving block exclusive-scans bsum inline (valid for nb <= 256).

__global__ void scan1_kernel(const int* __restrict__ cnt, int* __restrict__ rp_part,
                             int* __restrict__ bsum, int n,
                             int* __restrict__ done, int doInline) {
    __shared__ int s[256];
    __shared__ int s2[256];
    __shared__ int lastFlag;
    int tid = threadIdx.x;
    int i = blockIdx.x * 256 + tid;
    int v = (i < n) ? ((cnt[i] + 7) & ~7) : 0;
    s[tid] = v;
    __syncthreads();
    for (int off = 1; off < 256; off <<= 1) {
        int t = (tid >= off) ? s[tid - off] : 0;
        __syncthreads();
        s[tid] += t;
        __syncthreads();
    }
    if (i <= n) rp_part[i] = s[tid] - v;
    if (tid == 255) bsum[blockIdx.x] = s[255];

    if (!doInline) return;
    __threadfence();
    if (tid == 255) lastFlag = (atomicAdd(done, 1) == (int)gridDim.x - 1);
    __syncthreads();
    if (!lastFlag) return;
    int nb = (int)gridDim.x;
    int w = (tid < nb) ? bsum[tid] : 0;
    s2[tid] = w;
    __syncthreads();
    for (int off = 1; off < 256; off <<= 1) {
        int t = (tid >= off) ? s2[tid - off] : 0;
        __syncthreads();
        s2[tid] += t;
        __syncthreads();
    }
    if (tid < nb) bsum[tid] = s2[tid] - w;
}

__global__ void scan2_kernel(int* __restrict__ bsum, int nb) {  // fallback, nb > 256
    __shared__ int s[256];
    int tid = threadIdx.x;
    int v = (tid < nb) ? bsum[tid] : 0;
    s[tid] = v;
    __syncthreads();
    for (int off = 1; off < 256; off <<= 1) {
        int t = (tid >= off) ? s[tid - off] : 0;
        __syncthreads();
        s[tid] += t;
        __syncthreads();
    }
    if (tid < nb) bsum[tid] = s[tid] - v;
}

// esrc entries are 16-bit node ids (N<65536); scatter region ~1.9MB -> L2-resident.
__global__ void scan3_fill_kernel(const int* __restrict__ rp_part, const int* __restrict__ bsum,
                                  int* __restrict__ row_ptr,
                                  const int* __restrict__ src, const int* __restrict__ dst,
                                  const int* __restrict__ rank, const int* __restrict__ cnt,
                                  unsigned short* __restrict__ esrc,
                                  int n, int E) {
    int gid = blockIdx.x * blockDim.x + threadIdx.x;
    if (gid <= n) row_ptr[gid] = rp_part[gid] + bsum[gid >> 8];
    if (gid < n) {
        int st = rp_part[gid] + bsum[gid >> 8];
        int c = cnt[gid];
        int pe = (c + 7) & ~7;
        for (int j = c; j < pe; ++j) esrc[st + j] = (unsigned short)n;  // zero-row id
    }
    if (gid < E) {
        int d = dst[gid];
        if ((unsigned)d < (unsigned)n)
            esrc[rp_part[d] + bsum[d >> 8] + rank[gid]] = (unsigned short)src[gid];
    }
}

// ---------------- fused layer: int8 gather -> GEMM1(relu) -> GEMM2 [-> GEMM3(relu) -> GEMM4] ----------------
// Rounds 0-11: gather floor ~40cy/CU per row, invariant to request width / pipeline depth /
// bytes / chunking. Plain loads (R11: nontemporal loads REGRESSED +10% -> L1/L2 allocation
// has real reuse value). int8 rows (128B + per-row fp32 scale) halve HBM traffic.
// NOTE: __launch_bounds__(256,8) correlated with container failures (R6,R9); keep 6.

template <bool HEAD>
__launch_bounds__(256, 6)
__global__ void layer_kernel(const char* __restrict__ hq, const float* __restrict__ sIn,
                             const int* __restrict__ rp,
                             const unsigned short* __restrict__ esrc,
                             const unsigned short* __restrict__ W1t,
                             const float* __restrict__ b1,
                             const unsigned short* __restrict__ W2t,
                             const float* __restrict__ b2,
                             const unsigned short* __restrict__ W3t,
                             const float* __restrict__ b3,
                             const unsigned short* __restrict__ W4t,
                             const float* __restrict__ b4,
                             char* __restrict__ outq, float* __restrict__ outs,
                             float* __restrict__ outp, int M) {
    constexpr int LDA = 128 + 8;
    constexpr int CAP = 1024;
    __shared__ __align__(16) unsigned short As[16][LDA];
    __shared__ __align__(16) unsigned short Zs[16][LDA];
    __shared__ __align__(16) int2 sIdx[CAP];

    int tid = threadIdx.x;
    int wave = __builtin_amdgcn_readfirstlane(tid >> 6);
    int lane = tid & 63;
    int row0 = blockIdx.x * 16;
    int nd0 = row0 + wave * 4;

    const char* hc = hq;
    unsigned voff = (unsigned)lane << 1;   // 2 int8 cols per lane

    int wbv = rp[row0];
    int Cv = rp[min(row0 + 16, M)] - wbv;
    int wb = __builtin_amdgcn_readfirstlane(wbv);
    int C = __builtin_amdgcn_readfirstlane(Cv);

    int b[4], e[4];
#pragma unroll
    for (int i = 0; i < 4; ++i) {
        int ndc = min(nd0 + i, M);
        int nd1 = min(nd0 + i + 1, M);
        b[i] = rp[ndc] - wb;
        e[i] = rp[nd1] - wb;
    }

    float a0[4] = {0.f, 0.f, 0.f, 0.f}, a1[4] = {0.f, 0.f, 0.f, 0.f};

    for (int p0 = 0; p0 < C; p0 += CAP) {
        int cend = min(C, p0 + CAP);
        for (int i = tid; i < cend - p0; i += 256) {
            int id = esrc[wb + p0 + i];
            sIdx[i] = make_int2(id << 7, __float_as_int(sIn[id]));
        }
        __syncthreads();
#pragma unroll
        for (int i = 0; i < 4; ++i) {
            int nb = max(b[i], p0) - p0;
            int ne = min(e[i], cend) - p0;
            if (nb < ne) {
                int2 ia[8];
                unsigned ua[8];
#pragma unroll
                for (int t = 0; t < 8; ++t) ia[t] = sIdx[nb + t];
#pragma unroll
                for (int t = 0; t < 8; ++t)
                    ua[t] = *(const unsigned short*)(hc + (unsigned)ia[t].x + voff);
                for (int r = nb + 8; r < ne; r += 8) {
                    int2 ib[8];
                    unsigned ub[8];
#pragma unroll
                    for (int t = 0; t < 8; ++t) ib[t] = sIdx[r + t];
#pragma unroll
                    for (int t = 0; t < 8; ++t)
                        ub[t] = *(const unsigned short*)(hc + (unsigned)ib[t].x + voff);
#pragma unroll
                    for (int t = 0; t < 8; ++t) accI(a0[i], a1[i], ua[t], __int_as_float(ia[t].y));
#pragma unroll
                    for (int t = 0; t < 8; ++t) { ia[t] = ib[t]; ua[t] = ub[t]; }
                }
#pragma unroll
                for (int t = 0; t < 8; ++t) accI(a0[i], a1[i], ua[t], __int_as_float(ia[t].y));
            }
        }
        __syncthreads();
    }

    // add self, pack bf16 to LDS
#pragma unroll
    for (int i = 0; i < 4; ++i) {
        int ndc = min(nd0 + i, M);
        unsigned su = *(const unsigned short*)(hc + ((size_t)(unsigned)ndc << 7) + voff);
        accI(a0[i], a1[i], su, sIn[ndc]);
        unsigned pv = (unsigned)f2bf(a0[i]) | ((unsigned)f2bf(a1[i]) << 16);
        *(unsigned*)&As[wave * 4 + i][lane * 2] = pv;
    }
    __syncthreads();

    int quad = lane >> 4;
    int l16 = lane & 15;

    // ---- GEMM1: Zs = relu(As @ W1 + b1) ----
    bf16x8 af[4];
#pragma unroll
    for (int kt = 0; kt < 4; ++kt)
        af[kt] = *(const bf16x8*)(&As[l16][kt * 32 + quad * 8]);
#pragma unroll
    for (int p = 0; p < 2; ++p) {
        int ncol = (wave * 2 + p) * 16 + l16;
        const unsigned short* wp = W1t + ncol * 128 + quad * 8;
        f32x4 a = {0.f, 0.f, 0.f, 0.f};
#pragma unroll
        for (int kt = 0; kt < 4; ++kt)
            a = __builtin_amdgcn_mfma_f32_16x16x32_bf16(
                af[kt], *(const bf16x8*)(wp + kt * 32), a, 0, 0, 0);
        float bs = b1[ncol];
#pragma unroll
        for (int r = 0; r < 4; ++r) {
            float v = a[r] + bs;
            if (v < 0.f) v = 0.f;
            Zs[quad * 4 + r][ncol] = f2bf(v);
        }
    }
    __syncthreads();

    // ---- GEMM2: relu(Zs @ W2 + b2) ----
    bf16x8 zf[4];
#pragma unroll
    for (int kt = 0; kt < 4; ++kt)
        zf[kt] = *(const bf16x8*)(&Zs[l16][kt * 32 + quad * 8]);

    if (!HEAD) {
        __shared__ float Fs[16][132];
#pragma unroll
        for (int p = 0; p < 2; ++p) {
            int ncol = (wave * 2 + p) * 16 + l16;
            const unsigned short* wp = W2t + ncol * 128 + quad * 8;
            f32x4 a = {0.f, 0.f, 0.f, 0.f};
#pragma unroll
            for (int kt = 0; kt < 4; ++kt)
                a = __builtin_amdgcn_mfma_f32_16x16x32_bf16(
                    zf[kt], *(const bf16x8*)(wp + kt * 32), a, 0, 0, 0);
            float bs = b2[ncol];
#pragma unroll
            for (int r = 0; r < 4; ++r) {
                float v = a[r] + bs;
                if (v < 0.f) v = 0.f;
                Fs[quad * 4 + r][ncol] = v;
            }
        }
        __syncthreads();
        // quantize 16 rows to int8 + per-row scale (16 threads per row, 8 cols each)
        {
            int row = tid >> 4;
            int c0 = (tid & 15) * 8;
            float v8[8];
            float m = 0.f;
#pragma unroll
            for (int j = 0; j < 8; ++j) { v8[j] = Fs[row][c0 + j]; m = fmaxf(m, v8[j]); }
#pragma unroll
            for (int d = 8; d >= 1; d >>= 1) m = fmaxf(m, __shfl_xor(m, d));
            float inv = m > 0.f ? 127.f / m : 0.f;
            unsigned w0 = 0, w1 = 0;
#pragma unroll
            for (int j = 0; j < 4; ++j) {
                w0 |= (unsigned)(__float2int_rn(v8[j] * inv) & 0xff) << (8 * j);
                w1 |= (unsigned)(__float2int_rn(v8[4 + j] * inv) & 0xff) << (8 * j);
            }
            int grow = row0 + row;
            if (grow < M) {
                uint2 pk = make_uint2(w0, w1);
                ((uint2*)(outq + (size_t)grow * 128))[tid & 15] = pk;
                if ((tid & 15) == 0) outs[grow] = m * (1.f / 127.f);
            }
        }
    } else {
#pragma unroll
        for (int p = 0; p < 2; ++p) {
            int ncol = (wave * 2 + p) * 16 + l16;
            const unsigned short* wp = W2t + ncol * 128 + quad * 8;
            f32x4 a = {0.f, 0.f, 0.f, 0.f};
#pragma unroll
            for (int kt = 0; kt < 4; ++kt)
                a = __builtin_amdgcn_mfma_f32_16x16x32_bf16(
                    zf[kt], *(const bf16x8*)(wp + kt * 32), a, 0, 0, 0);
            float bs = b2[ncol];
#pragma unroll
            for (int r = 0; r < 4; ++r) {
                float v = a[r] + bs;
                if (v < 0.f) v = 0.f;
                As[quad * 4 + r][ncol] = f2bf(v);
            }
        }
        __syncthreads();
        // ---- GEMM3: Zs = relu(As @ W3 + b3) ----
        bf16x8 hf[4];
#pragma unroll
        for (int kt = 0; kt < 4; ++kt)
            hf[kt] = *(const bf16x8*)(&As[l16][kt * 32 + quad * 8]);
#pragma unroll
        for (int p = 0; p < 2; ++p) {
            int ncol = (wave * 2 + p) * 16 + l16;
            const unsigned short* wp = W3t + ncol * 128 + quad * 8;
            f32x4 a = {0.f, 0.f, 0.f, 0.f};
#pragma unroll
            for (int kt = 0; kt < 4; ++kt)
                a = __builtin_amdgcn_mfma_f32_16x16x32_bf16(
                    hf[kt], *(const bf16x8*)(wp + kt * 32), a, 0, 0, 0);
            float bs = b3[ncol];
#pragma unroll
            for (int r = 0; r < 4; ++r) {
                float v = a[r] + bs;
                if (v < 0.f) v = 0.f;
                Zs[quad * 4 + r][ncol] = f2bf(v);
            }
        }
        __syncthreads();
        // ---- GEMM4: d_out = Zs @ W4 + b4 (fp32, 64 cols) ----
        bf16x8 gf[4];
#pragma unroll
        for (int kt = 0; kt < 4; ++kt)
            gf[kt] = *(const bf16x8*)(&Zs[l16][kt * 32 + quad * 8]);
        {
            int ncol = wave * 16 + l16;
            const unsigned short* wp = W4t + ncol * 128 + quad * 8;
            f32x4 a = {0.f, 0.f, 0.f, 0.f};
#pragma unroll
            for (int kt = 0; kt < 4; ++kt)
                a = __builtin_amdgcn_mfma_f32_16x16x32_bf16(
                    gf[kt], *(const bf16x8*)(wp + kt * 32), a, 0, 0, 0);
            float bs = b4[ncol];
#pragma unroll
            for (int r = 0; r < 4; ++r) {
                int grow = row0 + quad * 4 + r;
                if (grow < M)
                    outp[(size_t)grow * 64 + ncol] = a[r] + bs;
            }
        }
    }
}

// ---------------- launch ----------------

extern "C" void kernel_launch(void* const* d_in, const int* in_sizes, int n_in,
                              void* d_out, int out_size, void* d_ws, size_t ws_size,
                              hipStream_t stream) {
    const float* x = (const float*)d_in[0];
    const int* ei = (const int*)d_in[1];
    int N = in_sizes[0] / DH;
    int E = in_sizes[1] / 2;
    const int* src = ei;
    const int* dstv = ei + E;
    int Epad = E + 7 * N + 1024;

    char* ws = (char*)d_ws;
    size_t off = 0;
    auto alloc = [&](size_t bytes) -> void* {
        void* p = ws + off;
        off += (bytes + 255) & ~(size_t)255;
        return p;
    };
    // int8 feature buffers, N+1 rows (row N = zero); per-row fp32 scales
    char* xq  = (char*)alloc((size_t)(N + 1) * 128);
    char* hAq = (char*)alloc((size_t)(N + 1) * 128);
    char* hBq = (char*)alloc((size_t)(N + 1) * 128);
    float* sx = (float*)alloc((size_t)(N + 1) * 4);
    float* sA = (float*)alloc((size_t)(N + 1) * 4);
    float* sB = (float*)alloc((size_t)(N + 1) * 4);
    unsigned short* wt[8];
    for (int m = 0; m < 8; ++m) wt[m] = (unsigned short*)alloc(16384 * 2);
    int* cnt     = (int*)alloc((size_t)(N + 1) * 4);  // cnt[N] = scan done-counter
    int* rp_part = (int*)alloc((size_t)(N + 1) * 4);
    int* row_ptr = (int*)alloc((size_t)(N + 1) * 4);
    int* rank    = (int*)alloc((size_t)E * 4);
    int* bsum    = (int*)alloc(1024 * 4);
    unsigned short* esrc = (unsigned short*)alloc((size_t)Epad * 2);

    WPrep wp;
    wp.src[0] = (const float*)d_in[2];
    wp.src[1] = (const float*)d_in[4];
    wp.src[2] = (const float*)d_in[6];
    wp.src[3] = (const float*)d_in[8];
    wp.src[4] = (const float*)d_in[10];
    wp.src[5] = (const float*)d_in[12];
    wp.src[6] = (const float*)d_in[14];
    wp.src[7] = (const float*)d_in[16];
    for (int m = 0; m < 8; ++m) wp.dst[m] = wt[m];

    hipMemsetAsync(cnt, 0, (size_t)(N + 1) * 4, stream);

    int nA = N * 32;
    int conv_items = nA + 7 * 16384 + 8192 + 99 + E;
    prep_conv_kernel<<<(conv_items + 255) / 256, 256, 0, stream>>>(
        x, xq, sx, hAq, sA, hBq, sB, nA, wp, cnt, rank, dstv, E, N);

    int nb = (N + 1 + 255) / 256;
    int eb = (E + 255) / 256;
    int doInline = (nb <= 256) ? 1 : 0;
    scan1_kernel<<<nb, 256, 0, stream>>>(cnt, rp_part, bsum, N, &cnt[N], doInline);
    if (!doInline) scan2_kernel<<<1, 256, 0, stream>>>(bsum, nb);
    scan3_fill_kernel<<<eb, 256, 0, stream>>>(rp_part, bsum, row_ptr,
                                              src, dstv, rank, cnt, esrc, N, E);

    int gb = (N + 15) / 16;

    const float* c1b1 = (const float*)d_in[3];
    const float* c1b2 = (const float*)d_in[5];
    const float* c2b1 = (const float*)d_in[7];
    const float* c2b2 = (const float*)d_in[9];
    const float* c3b1 = (const float*)d_in[11];
    const float* c3b2 = (const float*)d_in[13];
    const float* l1b  = (const float*)d_in[15];
    const float* l2b  = (const float*)d_in[17];

    layer_kernel<false><<<gb, 256, 0, stream>>>(
        xq, sx, row_ptr, esrc, wt[0], c1b1, wt[1], c1b2,
        nullptr, nullptr, nullptr, nullptr, hAq, sA, nullptr, N);
    layer_kernel<false><<<gb, 256, 0, stream>>>(
        hAq, sA, row_ptr, esrc, wt[2], c2b1, wt[3], c2b2,
        nullptr, nullptr, nullptr, nullptr, hBq, sB, nullptr, N);
    layer_kernel<true><<<gb, 256, 0, stream>>>(
        hBq, sB, row_ptr, esrc, wt[4], c3b1, wt[5], c3b2,
        wt[6], l1b, wt[7], l2b, nullptr, nullptr, (float*)d_out, N);
}